// Round 9
// baseline (422.959 us; speedup 1.0000x reference)
//
#include <hip/hip_runtime.h>
#include <hip/hip_bf16.h>

typedef unsigned int uint;
typedef unsigned short ushort_t;
typedef unsigned long long u64;
typedef __attribute__((ext_vector_type(8))) short short8;
typedef __attribute__((ext_vector_type(4))) short short4b;
typedef __attribute__((ext_vector_type(4))) float floatx4;

#define NB 8
#define NP 4096
#define ND 128
#define NK 16
#define NC 64
#define NPTS 32768   // NB*NP
#define CAP 1280     // candidate buffer; lane-min threshold keeps cnt ~20-60 typically

__device__ __forceinline__ float bf2f(ushort_t h){ return __uint_as_float(((uint)h)<<16); }
__device__ __forceinline__ ushort_t f2bf(float f){
  uint u = __float_as_uint(f);
  u = u + 0x7FFFu + ((u>>16)&1u);
  return (ushort_t)(u>>16);
}
__device__ __forceinline__ uint pack2(float a, float b){
  return (uint)f2bf(a) | ((uint)f2bf(b) << 16);
}
// dtype-polymorphic input load (f32=1: fp32 array, f32=0: bf16 array)
__device__ __forceinline__ float ldin(const void* p, long i, int f32){
  return f32 ? ((const float*)p)[i] : bf2f(((const ushort_t*)p)[i]);
}
// dtype-polymorphic output store
__device__ __forceinline__ void stout(void* o, long i, float v, int f32){
  if (f32) ((float*)o)[i] = v; else ((ushort_t*)o)[i] = f2bf(v);
}
// k-column permutation for h2/h3 segments of WTB2/WTC3: maps B-frag slot
// k = t*32 + q*8 + j to the canonical C-layout feature (2t+(j>>2))*16+4q+(j&3),
// so a lane's packed C registers ARE the next layer's B fragment (no shuffle).
__device__ __forceinline__ int permk(int k){
  int t = k >> 5, qq = (k >> 3) & 3, j = k & 7;
  return ((2*t + (j >> 2)) << 4) + (qq << 2) + (j & 3);
}

// ---------------- kernel D: detect input dtype ----------------
__global__ __launch_bounds__(256) void k_detect(const uint* __restrict__ w, int* __restrict__ flag){
  __shared__ int cnt;
  if (threadIdx.x == 0) cnt = 0;
  __syncthreads();
  int c = 0;
  for (int i = threadIdx.x; i < 512; i += 256){
    uint u = w[i];
    uint e = (u >> 7) & 0xFFu;
    c += (e >= 100u && e < 128u) ? 1 : 0;
  }
  atomicAdd(&cnt, c);
  __syncthreads();
  if (threadIdx.x == 0) *flag = (cnt < 256) ? 1 : 0;   // 1 => fp32 inputs/outputs
}

// ---------------- kernel 0: pos -> float4 {x,y,z,sq} ----------------
__global__ __launch_bounds__(256) void k_posf(const void* __restrict__ pos, float4* __restrict__ posf,
                                              const int* __restrict__ flag){
#pragma clang fp contract(off)
  int f32 = *flag;
  int p = blockIdx.x*256 + threadIdx.x;
  if (p >= NPTS) return;
  float x = ldin(pos, (long)p*3+0, f32);
  float y = ldin(pos, (long)p*3+1, f32);
  float z = ldin(pos, (long)p*3+2, f32);
  float px = x*x; float py = y*y; float pz = z*z;
  float sq = (px + py) + pz;   // match np.sum(pos*pos,-1) sequential order
  posf[p] = make_float4(x, y, z, sq);
}

// ---------------- kernel 1: exact 17-NN selection (one block per query) ----------------
__global__ __launch_bounds__(256) void k_knn(const float4* __restrict__ posf, int* __restrict__ knn){
#pragma clang fp contract(off)
  __shared__ u64 scand[CAP];
  __shared__ int scnt;
  __shared__ uint sut;
  int qid = blockIdx.x;
  int b = qid >> 12;
  int tid = threadIdx.x;
  int lane = tid & 63;
  if (tid == 0){ scnt = 0; sut = 0xFFFFFFFFu; }
  __syncthreads();
  const float4 q = posf[qid];
  int jbase = b << 12;
  float d2[16]; uint ub[16];
  #pragma unroll
  for (int s = 0; s < 16; ++s){
    int j = s*256 + tid;
    float4 pj = posf[jbase + j];
    float ax = q.x*pj.x; float ay = q.y*pj.y; float az = q.z*pj.z;
    float dot = (ax + ay) + az;                 // match np einsum order
    float t  = q.w + pj.w;                      // sq_i + sq_j (one rounding)
    float v  = t - 2.0f*dot;                    // 2*dot exact, one rounding
    d2[s] = v;
    ub[s] = __float_as_uint(fmaxf(v, 0.0f));    // nonneg float: uint order == float order
  }
  // per-lane min (register-only), then ballot binary search over lane-minima
  uint lm = ub[0];
  #pragma unroll
  for (int s = 1; s < 16; ++s) lm = (ub[s] < lm) ? ub[s] : lm;
  int lo = 0, hi = 4095;
  while (lo < hi){
    int mid = (lo + hi) >> 1;
    uint T = (uint)(mid+1) << 19;
    u64 bal = __ballot(lm < T);
    if (__popcll(bal) >= 17) hi = mid; else lo = mid + 1;
  }
  if (lane == 0) atomicMin(&sut, (uint)(lo+1) << 19);
  __syncthreads();
  uint ut = sut;
  #pragma unroll
  for (int s = 0; s < 16; ++s){
    if (ub[s] < ut){
      int p = atomicAdd(&scnt, 1);
      if (p < CAP){
        uint w = __float_as_uint(d2[s]);
        uint sd = w ^ ((w & 0x80000000u) ? 0xFFFFFFFFu : 0x80000000u); // signed monotone map
        scand[p] = (((u64)sd) << 32) | (uint)(s*256 + tid);
      }
    }
  }
  __syncthreads();
  int cnt = scnt; if (cnt > CAP) cnt = CAP;
  for (int base = 0; base < cnt; base += 256){
    int ci = base + tid;
    u64 mykey = (ci < cnt) ? scand[ci] : ~0ull;
    int r = 0;
    for (int i = 0; i < cnt; ++i){
      r += (scand[i] < mykey) ? 1 : 0;
    }
    if (ci < cnt && r >= 1 && r <= 16){
      knn[qid*16 + (r-1)] = (int)(mykey & 0xFFFFFFFFu);  // local j in [0,4096)
    }
  }
}

// ---------------- kernel W: weight prep ----------------
// WTB2/WTC3 h2/h3 k-columns are permuted by permk so k_edge needs no
// register repack between layers (h1 columns stay identity).
__global__ __launch_bounds__(256) void k_wprep(const void* __restrict__ Wf, const void* __restrict__ bfv,
                        const void* __restrict__ Wm1, const void* __restrict__ bm1,
                        const void* __restrict__ Wm2, const void* __restrict__ bm2,
                        const void* __restrict__ Wl, const void* __restrict__ bl,
                        ushort_t* __restrict__ WcatT, float* __restrict__ biasT,
                        ushort_t* __restrict__ WTA1, ushort_t* __restrict__ WTB2, ushort_t* __restrict__ WTC3,
                        const int* __restrict__ flag){
  int f32 = *flag;
  int id = blockIdx.x*256 + threadIdx.x;
  if (id < 40960){
    int n = id >> 7, k = id & 127;
    float v;
    if (n < 64)       v = ldin(Wf, (long)k*64 + n, f32) - ldin(Wf, (long)(256+k)*64 + n, f32);
    else if (n < 128) v = ldin(Wf, (long)(128+k)*64 + (n-64), f32) + ldin(Wf, (long)(256+k)*64 + (n-64), f32);
    else if (n < 192) v = ldin(Wm1, (long)(64+k)*64 + (n-128), f32);
    else if (n < 256) v = ldin(Wm2, (long)(128+k)*64 + (n-192), f32);
    else              v = ldin(Wl, (long)(192+k)*64 + (n-256), f32);
    WcatT[id] = f2bf(v);
  } else if (id < 41280){
    int n = id - 40960;
    float bv;
    if (n < 64)       bv = ldin(bfv, n, f32);
    else if (n < 128) bv = 0.0f;
    else if (n < 192) bv = ldin(bm1, n-128, f32);
    else if (n < 256) bv = ldin(bm2, n-192, f32);
    else              bv = ldin(bl, n-256, f32);
    biasT[n] = bv;
  } else if (id < 45376){      // WTA1 64x64 (k identity: h1 is built in natural order)
    int t = id - 41280; int n = t >> 6, k = t & 63;
    WTA1[t] = f2bf(ldin(Wm1, (long)k*64 + n, f32));
  } else if (id < 53568){      // WTB2 64x128: k<64 h2 (permuted), k>=64 h1 (identity)
    int t = id - 45376; int n = t >> 7, k = t & 127;
    int ks = (k < 64) ? permk(k) : k;
    WTB2[t] = f2bf(ldin(Wm2, (long)ks*64 + n, f32));
  } else if (id < 65856){      // WTC3 64x192: h3 perm | h2 perm | h1 identity
    int t = id - 53568; int n = t / 192, k = t % 192;
    int ks = (k < 64) ? permk(k) : ((k < 128) ? (64 + permk(k - 64)) : k);
    WTC3[t] = f2bf(ldin(Wl, (long)ks*64 + n, f32));
  }
}

// ---------------- kernel 2: P = X @ Wcat + bias  (bf16 out, rows 32768 x 320) ----------------
__global__ __launch_bounds__(256) void k_pgemm(const void* __restrict__ xv, const ushort_t* __restrict__ WcatT,
                                               const float* __restrict__ biasT, ushort_t* __restrict__ P,
                                               const int* __restrict__ flag){
  int f32 = *flag;
  int wave = threadIdx.x >> 6, lane = threadIdx.x & 63;
  int rowbase = blockIdx.x*64 + wave*16;
  int quad = lane >> 4, col = lane & 15;
  floatx4 acc[20];
  #pragma unroll
  for (int i = 0; i < 20; ++i) acc[i] = (floatx4){0.f,0.f,0.f,0.f};
  #pragma unroll
  for (int kk = 0; kk < 4; ++kk){
    int k = kk*32 + quad*8;
    short8 a;
    if (f32){
      const float* xf = (const float*)xv + (long)(rowbase + col)*128 + k;
      #pragma unroll
      for (int i = 0; i < 8; ++i) a[i] = (short)f2bf(xf[i]);
    } else {
      a = *(const short8*)((const ushort_t*)xv + (long)(rowbase + col)*128 + k);
    }
    #pragma unroll
    for (int nt = 0; nt < 20; ++nt){
      short8 bb = *(const short8*)(WcatT + (nt*16 + col)*128 + k);
      acc[nt] = __builtin_amdgcn_mfma_f32_16x16x32_bf16(a, bb, acc[nt], 0, 0, 0);
    }
  }
  #pragma unroll
  for (int nt = 0; nt < 20; ++nt){
    float bv = biasT[nt*16 + col];
    #pragma unroll
    for (int r = 0; r < 4; ++r){
      int m = quad*4 + r;
      P[(long)(rowbase + m)*320 + nt*16 + col] = f2bf(acc[nt][r] + bv);
    }
  }
}

// ---------------- kernel 3: per-edge chain, barrier-free (one wave per query) ----------------
// Weights are the MFMA A-operand (m = out-feature), h is the B-operand
// (n = edge = lane&15). With WTB2/WTC3 k-columns permuted (permk), a lane's
// packed C-layout accumulators ARE the next layer's B fragment: the entire
// 4-layer chain runs in registers with no LDS and no __syncthreads.
// LDS is used only for the final max-over-edges transpose (1 barrier).
__global__ __launch_bounds__(128) void k_edge(const void* __restrict__ x, const ushort_t* __restrict__ P,
                                              const int* __restrict__ knn,
                                              const ushort_t* __restrict__ WTA1, const ushort_t* __restrict__ WTB2,
                                              const ushort_t* __restrict__ WTC3, void* __restrict__ out,
                                              const int* __restrict__ flag){
  __shared__ __align__(16) ushort_t sc[2][4][16*68];   // [wave][o,h3,h2,h1][edge*68+feat]
  int f32 = *flag;
  int wave = threadIdx.x >> 6, lane = threadIdx.x & 63;
  int qid = blockIdx.x*2 + wave;
  int b = qid >> 12;
  int q4 = lane >> 4, c = lane & 15;
  const ushort_t* Prow = P + (long)qid*320;
  union S8 { short8 v; uint2 h[2]; };

  // early independent loads (hide latency under the chain)
  float xa = ldin(x, (long)qid*128 + lane, f32);
  float xb = ldin(x, (long)qid*128 + 64 + lane, f32);
  int nbr = knn[qid*16 + c] & (NP - 1);   // mask: corrupt idx stays in-bounds
  const ushort_t* Pk = P + ((long)(b<<12) + nbr)*320 + 64;

  // h1 in B-layout: lane (q4,c) holds features {q4*8+j} (tile A) and {32+q4*8+j} (tile B) of edge c
  short8 kA = *(const short8*)(Pk + q4*8);
  short8 kB = *(const short8*)(Pk + 32 + q4*8);
  short8 qA = *(const short8*)(Prow + q4*8);
  short8 qB = *(const short8*)(Prow + 32 + q4*8);
  short8 h1A, h1B;
  #pragma unroll
  for (int i = 0; i < 8; ++i){
    h1A[i] = (short)f2bf(fmaxf(bf2f((ushort_t)qA[i]) + bf2f((ushort_t)kA[i]), 0.0f));
    h1B[i] = (short)f2bf(fmaxf(bf2f((ushort_t)qB[i]) + bf2f((ushort_t)kB[i]), 0.0f));
  }
  { // stage h1 for maxpool
    S8 t0, t1; t0.v = h1A; t1.v = h1B;
    ushort_t* s1 = sc[wave][3] + c*68;
    *(uint2*)(s1 + q4*8)          = t0.h[0];
    *(uint2*)(s1 + q4*8 + 4)      = t0.h[1];
    *(uint2*)(s1 + 32 + q4*8)     = t1.h[0];
    *(uint2*)(s1 + 32 + q4*8 + 4) = t1.h[1];
  }

  // layer 2: h2 = relu(A1^T-as-A @ h1-as-B + u1), K=64
  floatx4 acc2[4];
  #pragma unroll
  for (int mt = 0; mt < 4; ++mt) acc2[mt] = (floatx4){0.f,0.f,0.f,0.f};
  #pragma unroll
  for (int mt = 0; mt < 4; ++mt){
    const ushort_t* wr = WTA1 + (mt*16 + c)*64 + q4*8;
    acc2[mt] = __builtin_amdgcn_mfma_f32_16x16x32_bf16(*(const short8*)wr,        h1A, acc2[mt], 0, 0, 0);
    acc2[mt] = __builtin_amdgcn_mfma_f32_16x16x32_bf16(*(const short8*)(wr + 32), h1B, acc2[mt], 0, 0, 0);
  }
  short8 h2A, h2B;
  {
    uint p0[4], p1[4];
    #pragma unroll
    for (int mt = 0; mt < 4; ++mt){
      short4b u1s = *(const short4b*)(Prow + 128 + mt*16 + q4*4);
      float v0 = fmaxf(acc2[mt][0] + bf2f((ushort_t)u1s[0]), 0.0f);
      float v1 = fmaxf(acc2[mt][1] + bf2f((ushort_t)u1s[1]), 0.0f);
      float v2 = fmaxf(acc2[mt][2] + bf2f((ushort_t)u1s[2]), 0.0f);
      float v3 = fmaxf(acc2[mt][3] + bf2f((ushort_t)u1s[3]), 0.0f);
      p0[mt] = pack2(v0, v1); p1[mt] = pack2(v2, v3);
      uint2 w; w.x = p0[mt]; w.y = p1[mt];
      *(uint2*)(sc[wave][2] + c*68 + mt*16 + q4*4) = w;   // stage h2 (canonical feature order)
    }
    S8 B0, B1;
    B0.h[0].x = p0[0]; B0.h[0].y = p1[0]; B0.h[1].x = p0[1]; B0.h[1].y = p1[1];
    B1.h[0].x = p0[2]; B1.h[0].y = p1[2]; B1.h[1].x = p0[3]; B1.h[1].y = p1[3];
    h2A = B0.v; h2B = B1.v;   // valid B-frags thanks to permk'd WTB2/WTC3 columns
  }

  // layer 3: h3 = relu([h2|h1] @ B2 + u2), K=128 (k: h2 perm cols 0..63, h1 64..127)
  floatx4 acc3[4];
  #pragma unroll
  for (int mt = 0; mt < 4; ++mt) acc3[mt] = (floatx4){0.f,0.f,0.f,0.f};
  #pragma unroll
  for (int mt = 0; mt < 4; ++mt){
    const ushort_t* wr = WTB2 + (mt*16 + c)*128 + q4*8;
    acc3[mt] = __builtin_amdgcn_mfma_f32_16x16x32_bf16(*(const short8*)wr,        h2A, acc3[mt], 0, 0, 0);
    acc3[mt] = __builtin_amdgcn_mfma_f32_16x16x32_bf16(*(const short8*)(wr + 32), h2B, acc3[mt], 0, 0, 0);
    acc3[mt] = __builtin_amdgcn_mfma_f32_16x16x32_bf16(*(const short8*)(wr + 64), h1A, acc3[mt], 0, 0, 0);
    acc3[mt] = __builtin_amdgcn_mfma_f32_16x16x32_bf16(*(const short8*)(wr + 96), h1B, acc3[mt], 0, 0, 0);
  }
  short8 h3A, h3B;
  {
    uint p0[4], p1[4];
    #pragma unroll
    for (int mt = 0; mt < 4; ++mt){
      short4b u2s = *(const short4b*)(Prow + 192 + mt*16 + q4*4);
      float v0 = fmaxf(acc3[mt][0] + bf2f((ushort_t)u2s[0]), 0.0f);
      float v1 = fmaxf(acc3[mt][1] + bf2f((ushort_t)u2s[1]), 0.0f);
      float v2 = fmaxf(acc3[mt][2] + bf2f((ushort_t)u2s[2]), 0.0f);
      float v3 = fmaxf(acc3[mt][3] + bf2f((ushort_t)u2s[3]), 0.0f);
      p0[mt] = pack2(v0, v1); p1[mt] = pack2(v2, v3);
      uint2 w; w.x = p0[mt]; w.y = p1[mt];
      *(uint2*)(sc[wave][1] + c*68 + mt*16 + q4*4) = w;   // stage h3
    }
    S8 B0, B1;
    B0.h[0].x = p0[0]; B0.h[0].y = p1[0]; B0.h[1].x = p0[1]; B0.h[1].y = p1[1];
    B1.h[0].x = p0[2]; B1.h[0].y = p1[2]; B1.h[1].x = p0[3]; B1.h[1].y = p1[3];
    h3A = B0.v; h3B = B1.v;
  }

  // layer 4: o = [h3|h2|h1] @ C3 (u3 added after max), K=192
  floatx4 acc4[4];
  #pragma unroll
  for (int mt = 0; mt < 4; ++mt) acc4[mt] = (floatx4){0.f,0.f,0.f,0.f};
  #pragma unroll
  for (int mt = 0; mt < 4; ++mt){
    const ushort_t* wr = WTC3 + (mt*16 + c)*192 + q4*8;
    acc4[mt] = __builtin_amdgcn_mfma_f32_16x16x32_bf16(*(const short8*)wr,         h3A, acc4[mt], 0, 0, 0);
    acc4[mt] = __builtin_amdgcn_mfma_f32_16x16x32_bf16(*(const short8*)(wr + 32),  h3B, acc4[mt], 0, 0, 0);
    acc4[mt] = __builtin_amdgcn_mfma_f32_16x16x32_bf16(*(const short8*)(wr + 64),  h2A, acc4[mt], 0, 0, 0);
    acc4[mt] = __builtin_amdgcn_mfma_f32_16x16x32_bf16(*(const short8*)(wr + 96),  h2B, acc4[mt], 0, 0, 0);
    acc4[mt] = __builtin_amdgcn_mfma_f32_16x16x32_bf16(*(const short8*)(wr + 128), h1A, acc4[mt], 0, 0, 0);
    acc4[mt] = __builtin_amdgcn_mfma_f32_16x16x32_bf16(*(const short8*)(wr + 160), h1B, acc4[mt], 0, 0, 0);
  }
  #pragma unroll
  for (int mt = 0; mt < 4; ++mt){   // stage o (bf16-rounded; max commutes with monotone rounding)
    uint2 w; w.x = pack2(acc4[mt][0], acc4[mt][1]); w.y = pack2(acc4[mt][2], acc4[mt][3]);
    *(uint2*)(sc[wave][0] + c*68 + mt*16 + q4*4) = w;
  }

  __syncthreads();   // the only barrier: scratch write -> transposed read

  // maxpool over edges: lane = feature (0..63), read 16 edges per array
  {
    const ushort_t* s0 = sc[wave][0];
    const ushort_t* s1 = sc[wave][1];
    const ushort_t* s2 = sc[wave][2];
    const ushort_t* s3 = sc[wave][3];
    float mo = bf2f(s0[lane]), m3 = bf2f(s1[lane]), m2 = bf2f(s2[lane]), m1 = bf2f(s3[lane]);
    #pragma unroll
    for (int e = 1; e < 16; ++e){
      mo = fmaxf(mo, bf2f(s0[e*68 + lane]));
      m3 = fmaxf(m3, bf2f(s1[e*68 + lane]));
      m2 = fmaxf(m2, bf2f(s2[e*68 + lane]));
      m1 = fmaxf(m1, bf2f(s3[e*68 + lane]));
    }
    float u3f = bf2f(Prow[256 + lane]);
    long outb = (long)qid*384;
    stout(out, outb + lane,       mo + u3f, f32);
    stout(out, outb + 64  + lane, m3, f32);
    stout(out, outb + 128 + lane, m2, f32);
    stout(out, outb + 192 + lane, m1, f32);
    stout(out, outb + 256 + lane, xa, f32);
    stout(out, outb + 320 + lane, xb, f32);
  }
}

extern "C" void kernel_launch(void* const* d_in, const int* in_sizes, int n_in,
                              void* d_out, int out_size, void* d_ws, size_t ws_size,
                              hipStream_t stream){
  const void* x   = d_in[0];
  const void* pos = d_in[1];
  const void* Wf  = d_in[2];
  const void* bfv = d_in[3];
  const void* Wm1 = d_in[4];
  const void* bm1 = d_in[5];
  const void* Wm2 = d_in[6];
  const void* bm2 = d_in[7];
  const void* Wl  = d_in[8];
  const void* bl  = d_in[9];
  char* ws = (char*)d_ws;
  float4*   posf  = (float4*)(ws + 0);                 // 524288 B
  int*      knn   = (int*)(ws + 524288);               // 2097152 B
  ushort_t* P     = (ushort_t*)(ws + 2621440);         // 20971520 B
  ushort_t* WcatT = (ushort_t*)(ws + 23592960);        // 81920 B
  float*    biasT = (float*)(ws + 23674880);           // 1280 B
  ushort_t* WTA1  = (ushort_t*)(ws + 23676160);        // 8192 B
  ushort_t* WTB2  = (ushort_t*)(ws + 23684352);        // 16384 B
  ushort_t* WTC3  = (ushort_t*)(ws + 23700736);        // 24576 B
  int*      flag  = (int*)(ws + 23725312);             // 4 B (total ~22.63 MB)

  k_detect<<<1,     256, 0, stream>>>((const uint*)Wf, flag);
  k_posf <<<128,   256, 0, stream>>>(pos, posf, flag);
  k_wprep<<<258,   256, 0, stream>>>(Wf, bfv, Wm1, bm1, Wm2, bm2, Wl, bl, WcatT, biasT, WTA1, WTB2, WTC3, flag);
  k_knn  <<<32768, 256, 0, stream>>>(posf, knn);
  k_pgemm<<<512,   256, 0, stream>>>(x, WcatT, biasT, P, flag);
  k_edge <<<16384, 128, 0, stream>>>(x, P, knn, WTA1, WTB2, WTC3, d_out, flag);
}